// Round 1
// baseline (6450.423 us; speedup 1.0000x reference)
//
#include <hip/hip_runtime.h>
#include <cfloat>
#include <cstdint>

#define BATCH 16
#define PRIORS 3000
#define NCLS 201
#define NLBL 200           // NCLS - 1
#define TOPN 100
#define SCORE_THR 0.02f
#define NMS_THR 0.45f
#define CAP_MAX 65536

// ---------------------------------------------------------------------------
// Kernel A: decode boxes, per-image max coordinate (for the class-offset
// trick), zero the per-image candidate counters.
// ---------------------------------------------------------------------------
__global__ __launch_bounds__(256) void decode_kernel(
    const float* __restrict__ deltas,   // [B][P][4]
    const float* __restrict__ priors,   // [P][4]
    float* __restrict__ dec,            // [B][P][4]  (x1,y1,x2,y2, un-offset)
    float* __restrict__ offA,           // [B]        max(dec)+1
    int*   __restrict__ cnt)            // [B]
{
    const int b = blockIdx.x;
    const int tid = threadIdx.x;
    float lmax = -FLT_MAX;
    for (int p = tid; p < PRIORS; p += 256) {
        float4 d4 = ((const float4*)deltas)[(size_t)b * PRIORS + p];
        float4 pr = ((const float4*)priors)[p];
        float cx = d4.x * 0.1f * pr.z + pr.x;
        float cy = d4.y * 0.1f * pr.w + pr.y;
        float w  = expf(d4.z * 0.2f) * pr.z;
        float h  = expf(d4.w * 0.2f) * pr.w;
        float x1 = cx - 0.5f * w, y1 = cy - 0.5f * h;
        float x2 = cx + 0.5f * w, y2 = cy + 0.5f * h;
        ((float4*)dec)[(size_t)b * PRIORS + p] = make_float4(x1, y1, x2, y2);
        lmax = fmaxf(lmax, fmaxf(fmaxf(x1, y1), fmaxf(x2, y2)));
    }
    for (int d = 32; d > 0; d >>= 1)
        lmax = fmaxf(lmax, __shfl_xor(lmax, d, 64));
    __shared__ float wmax[4];
    if ((tid & 63) == 0) wmax[tid >> 6] = lmax;
    __syncthreads();
    if (tid == 0) {
        float m = fmaxf(fmaxf(wmax[0], wmax[1]), fmaxf(wmax[2], wmax[3]));
        offA[b] = m + 1.0f;
        cnt[b] = 0;
    }
}

// ---------------------------------------------------------------------------
// Kernel B: one wave per (b,p). Softmax over 201 classes, filter prob>0.02,
// append candidates (score, offset box, area, original flat index).
// ---------------------------------------------------------------------------
__global__ __launch_bounds__(256) void score_filter_kernel(
    const float*  __restrict__ obj,     // [B][P][NCLS]
    const float*  __restrict__ dec,     // [B][P][4]
    const float*  __restrict__ offA,    // [B]
    int*          __restrict__ cnt,     // [B]
    float*        __restrict__ sArr,    // [B][cap]
    float4*       __restrict__ boxArr,  // [B][cap]  offset boxes
    float*        __restrict__ areaArr, // [B][cap]
    int*          __restrict__ oidArr,  // [B][cap]  p*200 + (c-1)
    int cap)
{
    const int gw   = (int)((blockIdx.x * 256u + threadIdx.x) >> 6);
    const int lane = threadIdx.x & 63;
    if (gw >= BATCH * PRIORS) return;
    const int b = gw / PRIORS, p = gw % PRIORS;
    const float* x = obj + ((size_t)b * PRIORS + p) * NCLS;

    float v0 = x[lane];
    float v1 = x[lane + 64];
    float v2 = x[lane + 128];
    float v3 = (lane + 192 < NCLS) ? x[lane + 192] : -FLT_MAX;
    float mx = fmaxf(fmaxf(v0, v1), fmaxf(v2, v3));
    for (int d = 32; d > 0; d >>= 1) mx = fmaxf(mx, __shfl_xor(mx, d, 64));
    float e0 = expf(v0 - mx), e1 = expf(v1 - mx), e2 = expf(v2 - mx);
    float e3 = (lane + 192 < NCLS) ? expf(v3 - mx) : 0.0f;
    float se = e0 + e1 + e2 + e3;
    for (int d = 32; d > 0; d >>= 1) se += __shfl_xor(se, d, 64);

    float  ofb = offA[b];
    float4 db  = ((const float4*)dec)[(size_t)b * PRIORS + p];
    float  ev[4] = { e0, e1, e2, e3 };
#pragma unroll
    for (int k = 0; k < 4; ++k) {
        int c = lane + 64 * k;
        if (c >= 1 && c < NCLS) {
            float prob = ev[k] / se;
            if (prob > SCORE_THR) {
                int idx = atomicAdd(&cnt[b], 1);
                if (idx < cap) {
                    float lo  = (float)c * ofb;      // label * off, like the ref
                    float bx1 = db.x + lo, by1 = db.y + lo;
                    float bx2 = db.z + lo, by2 = db.w + lo;
                    size_t o = (size_t)b * cap + idx;
                    sArr[o]    = prob;
                    boxArr[o]  = make_float4(bx1, by1, bx2, by2);
                    areaArr[o] = (bx2 - bx1) * (by2 - by1);
                    oidArr[o]  = p * NLBL + (c - 1);
                }
            }
        }
    }
}

// ---------------------------------------------------------------------------
// Kernel C: one block per image. 100 iterations of greedy NMS:
//   argmax (tie-break: lowest original flat index, matching jnp.argmax),
//   output write, suppression sweep (IoU on offset boxes > 0.45 -> s=-1).
// ---------------------------------------------------------------------------
__global__ __launch_bounds__(1024) void nms_kernel(
    const float*  __restrict__ dec,
    const int*    __restrict__ cnt,
    float*        __restrict__ sArr,
    const float4* __restrict__ boxArr,
    const float*  __restrict__ areaArr,
    const int*    __restrict__ oidArr,
    float*        __restrict__ out,     // [B][TOPN][6]
    int cap)
{
    const int b = blockIdx.x;
    const int tid = threadIdx.x;
    int n = cnt[b]; if (n > cap) n = cap;
    const size_t base = (size_t)b * cap;
    float*        s   = sArr + base;
    const float4* bx  = boxArr + base;
    const float*  ar  = areaArr + base;
    const int*    oid = oidArr + base;

    __shared__ float rs[16]; __shared__ int ro[16]; __shared__ int rj[16];
    __shared__ float4 selBox; __shared__ float selArea;
    __shared__ int stop;

    for (int t = 0; t < TOPN; ++t) {
        // ---- block-wide argmax with tie-break on original index ----
        float bs = -2.0f; int bo = 0x7fffffff; int bj = 0;
        for (int j = tid; j < n; j += 1024) {
            float v = s[j];
            int o = oid[j];
            if (v > bs || (v == bs && o < bo)) { bs = v; bo = o; bj = j; }
        }
        for (int d = 32; d > 0; d >>= 1) {
            float os = __shfl_xor(bs, d, 64);
            int oo = __shfl_xor(bo, d, 64);
            int oj = __shfl_xor(bj, d, 64);
            if (os > bs || (os == bs && oo < bo)) { bs = os; bo = oo; bj = oj; }
        }
        if ((tid & 63) == 0) { int w = tid >> 6; rs[w] = bs; ro[w] = bo; rj[w] = bj; }
        __syncthreads();
        if (tid == 0) {
            float fs = rs[0]; int fo = ro[0]; int fj = rj[0];
            for (int w = 1; w < 16; ++w)
                if (rs[w] > fs || (rs[w] == fs && ro[w] < fo)) { fs = rs[w]; fo = ro[w]; fj = rj[w]; }
            if (fs > SCORE_THR) {
                stop = 0;
                selBox = bx[fj]; selArea = ar[fj];
                s[fj] = -1.0f;                       // matches .at[i].set(-1)
                int p = fo / NLBL;
                int c = fo - p * NLBL + 1;
                float4 db = ((const float4*)dec)[(size_t)b * PRIORS + p];
                float* o = out + ((size_t)b * TOPN + t) * 6;
                o[0] = fminf(fmaxf(db.x, 0.0f), 1.0f);
                o[1] = fminf(fmaxf(db.y, 0.0f), 1.0f);
                o[2] = fminf(fmaxf(db.z, 0.0f), 1.0f);
                o[3] = fminf(fmaxf(db.w, 0.0f), 1.0f);
                o[4] = fs;
                o[5] = (float)c;
            } else {
                stop = 1;
            }
        }
        __syncthreads();
        if (stop) {
            // everything remaining is suppressed -> zero rows t..99
            float* orow = out + ((size_t)b * TOPN + t) * 6;
            for (int k = tid; k < (TOPN - t) * 6; k += 1024) orow[k] = 0.0f;
            break;
        }
        const float4 sb = selBox; const float sa = selArea;
        // ---- suppression sweep ----
        for (int j = tid; j < n; j += 1024) {
            float4 q = bx[j];
            float ix1 = fmaxf(q.x, sb.x);
            float iy1 = fmaxf(q.y, sb.y);
            float ix2 = fminf(q.z, sb.z);
            float iy2 = fminf(q.w, sb.w);
            float inter = fmaxf(ix2 - ix1, 0.0f) * fmaxf(iy2 - iy1, 0.0f);
            float iou = inter / (ar[j] + sa - inter);   // NaN > thr == false, like jnp
            if (iou > NMS_THR) s[j] = -1.0f;
        }
        __syncthreads();
    }
}

// ---------------------------------------------------------------------------
extern "C" void kernel_launch(void* const* d_in, const int* in_sizes, int n_in,
                              void* d_out, int out_size, void* d_ws, size_t ws_size,
                              hipStream_t stream)
{
    const float* deltas = (const float*)d_in[0];
    const float* obj    = (const float*)d_in[1];
    const float* priors = (const float*)d_in[2];
    float* out = (float*)d_out;

    char* ws = (char*)d_ws;
    float* dec  = (float*)ws;                              // B*P*4 floats
    float* offA = dec + (size_t)BATCH * PRIORS * 4;        // B floats
    int*   cnt  = (int*)(offA + BATCH);                    // B ints
    size_t fixedBytes = ((size_t)BATCH * PRIORS * 4 + BATCH + BATCH) * 4;
    size_t candOff = (fixedBytes + 255) & ~(size_t)255;
    size_t avail = ws_size > candOff ? ws_size - candOff : 0;
    long cap = (long)(avail / ((size_t)BATCH * 28));       // 28 B / candidate
    if (cap > CAP_MAX) cap = CAP_MAX;
    if (cap < 1) cap = 1;

    float4* boxArr  = (float4*)(ws + candOff);
    float*  sArr    = (float*)(boxArr + (size_t)BATCH * cap);
    float*  areaArr = sArr + (size_t)BATCH * cap;
    int*    oidArr  = (int*)(areaArr + (size_t)BATCH * cap);

    decode_kernel<<<BATCH, 256, 0, stream>>>(deltas, priors, dec, offA, cnt);
    int nwaves = BATCH * PRIORS;                           // one wave per prior
    score_filter_kernel<<<(nwaves + 3) / 4, 256, 0, stream>>>(
        obj, dec, offA, cnt, sArr, boxArr, areaArr, oidArr, (int)cap);
    nms_kernel<<<BATCH, 1024, 0, stream>>>(
        dec, cnt, sArr, boxArr, areaArr, oidArr, out, (int)cap);
}

// Round 2
// 1150.306 us; speedup vs baseline: 5.6076x; 5.6076x over previous
//
#include <hip/hip_runtime.h>
#include <cfloat>
#include <cstdint>

#define BATCH 16
#define PRIORS 3000
#define NCLS 201
#define NLBL 200           // NCLS - 1
#define TOPN 100
#define SCORE_THR 0.02f
#define NMS_THR 0.45f
#define CAP_MAX 65536
#define PPB 16             // priors per block in score_filter (16 waves)
#define NBLKX ((PRIORS + PPB - 1) / PPB)   // 188

// ---------------------------------------------------------------------------
// Kernel A: decode boxes, per-image max coordinate (for the class-offset
// trick), zero the per-image candidate counters.
// ---------------------------------------------------------------------------
__global__ __launch_bounds__(256) void decode_kernel(
    const float* __restrict__ deltas,   // [B][P][4]
    const float* __restrict__ priors,   // [P][4]
    float* __restrict__ dec,            // [B][P][4]  (x1,y1,x2,y2, un-offset)
    float* __restrict__ offA,           // [B]        max(dec)+1
    int*   __restrict__ cnt)            // [B]
{
    const int b = blockIdx.x;
    const int tid = threadIdx.x;
    float lmax = -FLT_MAX;
    for (int p = tid; p < PRIORS; p += 256) {
        float4 d4 = ((const float4*)deltas)[(size_t)b * PRIORS + p];
        float4 pr = ((const float4*)priors)[p];
        float cx = d4.x * 0.1f * pr.z + pr.x;
        float cy = d4.y * 0.1f * pr.w + pr.y;
        float w  = expf(d4.z * 0.2f) * pr.z;
        float h  = expf(d4.w * 0.2f) * pr.w;
        float x1 = cx - 0.5f * w, y1 = cy - 0.5f * h;
        float x2 = cx + 0.5f * w, y2 = cy + 0.5f * h;
        ((float4*)dec)[(size_t)b * PRIORS + p] = make_float4(x1, y1, x2, y2);
        lmax = fmaxf(lmax, fmaxf(fmaxf(x1, y1), fmaxf(x2, y2)));
    }
    for (int d = 32; d > 0; d >>= 1)
        lmax = fmaxf(lmax, __shfl_xor(lmax, d, 64));
    __shared__ float wmax[4];
    if ((tid & 63) == 0) wmax[tid >> 6] = lmax;
    __syncthreads();
    if (tid == 0) {
        float m = fmaxf(fmaxf(wmax[0], wmax[1]), fmaxf(wmax[2], wmax[3]));
        offA[b] = m + 1.0f;
        cnt[b] = 0;
    }
}

// ---------------------------------------------------------------------------
// Kernel B (v2): block = 16 waves = 16 priors of ONE image.
// Per-wave softmax over 201 classes; candidates staged in LDS via LDS
// atomics; ONE global atomicAdd per block reserves a contiguous range;
// coalesced flush. (v1 did one global atomic per candidate -> 300 ns x
// 17.6k serialized per image = 5.3 ms. Guideline 12.)
// ---------------------------------------------------------------------------
__global__ __launch_bounds__(1024) void score_filter_kernel(
    const float*  __restrict__ obj,     // [B][P][NCLS]
    const float*  __restrict__ dec,     // [B][P][4]
    const float*  __restrict__ offA,    // [B]
    int*          __restrict__ cnt,     // [B]
    float*        __restrict__ sArr,    // [B][cap]
    float4*       __restrict__ boxArr,  // [B][cap]  offset boxes
    float*        __restrict__ areaArr, // [B][cap]
    int*          __restrict__ oidArr,  // [B][cap]  p*200 + (c-1)
    int cap)
{
    __shared__ float lprob[PPB * NLBL];   // worst case 3200 candidates
    __shared__ uint32_t lpc[PPB * NLBL];  // (p<<8) | c
    __shared__ int lcnt;
    __shared__ int gbase;

    const int b    = blockIdx.y;
    const int tid  = threadIdx.x;
    const int wave = tid >> 6;
    const int lane = tid & 63;
    const int p    = blockIdx.x * PPB + wave;

    if (tid == 0) lcnt = 0;
    __syncthreads();

    if (p < PRIORS) {
        const float* x = obj + ((size_t)b * PRIORS + p) * NCLS;
        float v0 = x[lane];
        float v1 = x[lane + 64];
        float v2 = x[lane + 128];
        float v3 = (lane + 192 < NCLS) ? x[lane + 192] : -FLT_MAX;
        float mx = fmaxf(fmaxf(v0, v1), fmaxf(v2, v3));
        for (int d = 32; d > 0; d >>= 1) mx = fmaxf(mx, __shfl_xor(mx, d, 64));
        float e0 = expf(v0 - mx), e1 = expf(v1 - mx), e2 = expf(v2 - mx);
        float e3 = (lane + 192 < NCLS) ? expf(v3 - mx) : 0.0f;
        float se = e0 + e1 + e2 + e3;
        for (int d = 32; d > 0; d >>= 1) se += __shfl_xor(se, d, 64);
        float inv = 1.0f / se;
        float ev[4] = { e0, e1, e2, e3 };
#pragma unroll
        for (int k = 0; k < 4; ++k) {
            int c = lane + 64 * k;
            if (c >= 1 && c < NCLS) {
                float prob = ev[k] * inv;
                if (prob > SCORE_THR) {
                    int li = atomicAdd(&lcnt, 1);        // LDS atomic: cheap
                    lprob[li] = prob;
                    lpc[li]   = ((uint32_t)p << 8) | (uint32_t)c;
                }
            }
        }
    }
    __syncthreads();

    const int nloc = lcnt;
    if (tid == 0 && nloc > 0) gbase = atomicAdd(&cnt[b], nloc);
    __syncthreads();

    if (nloc > 0) {
        const int base = gbase;
        const float ofb = offA[b];
        for (int j = tid; j < nloc; j += 1024) {
            int idx = base + j;
            if (idx >= cap) continue;
            uint32_t pc = lpc[j];
            int pp = (int)(pc >> 8);
            int c  = (int)(pc & 0xff);
            float4 db = ((const float4*)dec)[(size_t)b * PRIORS + pp];
            float lo  = (float)c * ofb;
            float bx1 = db.x + lo, by1 = db.y + lo;
            float bx2 = db.z + lo, by2 = db.w + lo;
            size_t o = (size_t)b * cap + idx;
            sArr[o]    = lprob[j];
            boxArr[o]  = make_float4(bx1, by1, bx2, by2);
            areaArr[o] = (bx2 - bx1) * (by2 - by1);
            oidArr[o]  = pp * NLBL + (c - 1);
        }
    }
}

// ---------------------------------------------------------------------------
// Kernel C: one block per image. 100 iterations of greedy NMS:
//   argmax (tie-break: lowest original flat index, matching jnp.argmax),
//   output write, suppression sweep (IoU on offset boxes > 0.45 -> s=-1).
// ---------------------------------------------------------------------------
__global__ __launch_bounds__(1024) void nms_kernel(
    const float*  __restrict__ dec,
    const int*    __restrict__ cnt,
    float*        __restrict__ sArr,
    const float4* __restrict__ boxArr,
    const float*  __restrict__ areaArr,
    const int*    __restrict__ oidArr,
    float*        __restrict__ out,     // [B][TOPN][6]
    int cap)
{
    const int b = blockIdx.x;
    const int tid = threadIdx.x;
    int n = cnt[b]; if (n > cap) n = cap;
    const size_t base = (size_t)b * cap;
    float*        s   = sArr + base;
    const float4* bx  = boxArr + base;
    const float*  ar  = areaArr + base;
    const int*    oid = oidArr + base;

    __shared__ float rs[16]; __shared__ int ro[16]; __shared__ int rj[16];
    __shared__ float4 selBox; __shared__ float selArea;
    __shared__ int stop;

    for (int t = 0; t < TOPN; ++t) {
        // ---- block-wide argmax with tie-break on original index ----
        float bs = -2.0f; int bo = 0x7fffffff; int bj = 0;
        for (int j = tid; j < n; j += 1024) {
            float v = s[j];
            int o = oid[j];
            if (v > bs || (v == bs && o < bo)) { bs = v; bo = o; bj = j; }
        }
        for (int d = 32; d > 0; d >>= 1) {
            float os = __shfl_xor(bs, d, 64);
            int oo = __shfl_xor(bo, d, 64);
            int oj = __shfl_xor(bj, d, 64);
            if (os > bs || (os == bs && oo < bo)) { bs = os; bo = oo; bj = oj; }
        }
        if ((tid & 63) == 0) { int w = tid >> 6; rs[w] = bs; ro[w] = bo; rj[w] = bj; }
        __syncthreads();
        if (tid == 0) {
            float fs = rs[0]; int fo = ro[0]; int fj = rj[0];
            for (int w = 1; w < 16; ++w)
                if (rs[w] > fs || (rs[w] == fs && ro[w] < fo)) { fs = rs[w]; fo = ro[w]; fj = rj[w]; }
            if (fs > SCORE_THR) {
                stop = 0;
                selBox = bx[fj]; selArea = ar[fj];
                s[fj] = -1.0f;                       // matches .at[i].set(-1)
                int p = fo / NLBL;
                int c = fo - p * NLBL + 1;
                float4 db = ((const float4*)dec)[(size_t)b * PRIORS + p];
                float* o = out + ((size_t)b * TOPN + t) * 6;
                o[0] = fminf(fmaxf(db.x, 0.0f), 1.0f);
                o[1] = fminf(fmaxf(db.y, 0.0f), 1.0f);
                o[2] = fminf(fmaxf(db.z, 0.0f), 1.0f);
                o[3] = fminf(fmaxf(db.w, 0.0f), 1.0f);
                o[4] = fs;
                o[5] = (float)c;
            } else {
                stop = 1;
            }
        }
        __syncthreads();
        if (stop) {
            // everything remaining is suppressed -> zero rows t..99
            float* orow = out + ((size_t)b * TOPN + t) * 6;
            for (int k = tid; k < (TOPN - t) * 6; k += 1024) orow[k] = 0.0f;
            break;
        }
        const float4 sb = selBox; const float sa = selArea;
        // ---- suppression sweep ----
        for (int j = tid; j < n; j += 1024) {
            float4 q = bx[j];
            float ix1 = fmaxf(q.x, sb.x);
            float iy1 = fmaxf(q.y, sb.y);
            float ix2 = fminf(q.z, sb.z);
            float iy2 = fminf(q.w, sb.w);
            float inter = fmaxf(ix2 - ix1, 0.0f) * fmaxf(iy2 - iy1, 0.0f);
            float iou = inter / (ar[j] + sa - inter);   // NaN > thr == false, like jnp
            if (iou > NMS_THR) s[j] = -1.0f;
        }
        __syncthreads();
    }
}

// ---------------------------------------------------------------------------
extern "C" void kernel_launch(void* const* d_in, const int* in_sizes, int n_in,
                              void* d_out, int out_size, void* d_ws, size_t ws_size,
                              hipStream_t stream)
{
    const float* deltas = (const float*)d_in[0];
    const float* obj    = (const float*)d_in[1];
    const float* priors = (const float*)d_in[2];
    float* out = (float*)d_out;

    char* ws = (char*)d_ws;
    float* dec  = (float*)ws;                              // B*P*4 floats
    float* offA = dec + (size_t)BATCH * PRIORS * 4;        // B floats
    int*   cnt  = (int*)(offA + BATCH);                    // B ints
    size_t fixedBytes = ((size_t)BATCH * PRIORS * 4 + BATCH + BATCH) * 4;
    size_t candOff = (fixedBytes + 255) & ~(size_t)255;
    size_t avail = ws_size > candOff ? ws_size - candOff : 0;
    long cap = (long)(avail / ((size_t)BATCH * 28));       // 28 B / candidate
    if (cap > CAP_MAX) cap = CAP_MAX;
    if (cap < 1) cap = 1;

    float4* boxArr  = (float4*)(ws + candOff);
    float*  sArr    = (float*)(boxArr + (size_t)BATCH * cap);
    float*  areaArr = sArr + (size_t)BATCH * cap;
    int*    oidArr  = (int*)(areaArr + (size_t)BATCH * cap);

    decode_kernel<<<BATCH, 256, 0, stream>>>(deltas, priors, dec, offA, cnt);
    dim3 sg(NBLKX, BATCH, 1);
    score_filter_kernel<<<sg, 1024, 0, stream>>>(
        obj, dec, offA, cnt, sArr, boxArr, areaArr, oidArr, (int)cap);
    nms_kernel<<<BATCH, 1024, 0, stream>>>(
        dec, cnt, sArr, boxArr, areaArr, oidArr, out, (int)cap);
}